// Round 8
// baseline (1559.490 us; speedup 1.0000x reference)
//
#include <hip/hip_runtime.h>
#include <hip/hip_bf16.h>

#define NIN 32
#define NHID 128
#define NOUT 16
#define SEQT 512
#define NB 256
#define RPW 40     // records per wave (4 waves x 40 = 160)

typedef __attribute__((ext_vector_type(8))) short s16x8;   // 8 bf16 (4 VGPRs) - MFMA A/B frag
typedef __attribute__((ext_vector_type(4))) float f32x4;   // MFMA C/D frag

// manual RNE f32->bf16 (inputs are finite/sane here)
__device__ __forceinline__ unsigned int f2bfbits(float f) {
    unsigned int u = __float_as_uint(f);
    return (u + 0x7fffu + ((u >> 16) & 1u)) >> 16;
}
__device__ __forceinline__ unsigned int packbf(float lo, float hi) {
    return f2bfbits(lo) | (f2bfbits(hi) << 16);
}

__device__ __forceinline__ float fsilu(float c) {
    return c * __builtin_amdgcn_rcpf(1.f + __expf(-c));
}

// Knots: t_m = -8.8 + 1.6*m (G=5, K=3, range [-4,4]); uniform -> closed-form
// cubic basis. No local arrays; cndmask trees on NAMED scalars.
// Verified PASS rounds 6-7 (absmax identical to original recursion).
struct E8 { float e0, e1, e2, e3, e4, e5, e6, e7, sil; };

__device__ __forceinline__ E8 feat8(float c) {
    const float t0 = -8.8f, inv_h = 0.625f;
    float u  = (c - t0) * inv_h;
    float uf = floorf(u);
    int   m0 = (int)uf;
    bool valid = (m0 >= 0) && (m0 <= 10);
    float f   = u - uf;
    float omf = 1.0f - f;
    float f2 = f * f, f3 = f2 * f;
    float omf3 = omf * omf * omf;
    const float c6 = 0.16666667f;
    float v0 = omf3 * c6;
    float v1 = __builtin_fmaf(3.0f, f3, __builtin_fmaf(-6.0f, f2, 4.0f)) * c6;
    float v2 = __builtin_fmaf(-3.0f, f3, __builtin_fmaf(3.0f, f + f2, 1.0f)) * c6;
    float v3 = f3 * c6;
    int jb = m0 - 3;
    int js = jb < 0 ? 0 : (jb > 4 ? 4 : jb);
    E8 r;
    r.sil = fsilu(c);
#define SELK(k) { int d = (k) - js; int idx = (k) - jb; \
    float s = (idx == 0) ? v0 : (idx == 1) ? v1 : (idx == 2) ? v2 : (idx == 3) ? v3 : 0.f; \
    r.e##k = (valid && d >= 0 && d <= 3) ? s : 0.f; }
    SELK(0) SELK(1) SELK(2) SELK(3) SELK(4) SELK(5) SELK(6) SELK(7)
#undef SELK
    return r;
}

// sb1 with K-pad guard (r >= RPW -> 0, address stays in-bounds)
__device__ __forceinline__ float sb1_pad(const float* __restrict__ sb1, int wbase, int r, int oo) {
    int rr = (r < RPW) ? r : 0;
    float v = sb1[(wbase + rr) * NHID + oo];
    return (r < RPW) ? v : 0.f;
}

// ---- X-macro lists ----
#define O8(X) X(0) X(1) X(2) X(3) X(4) X(5) X(6) X(7)
#define K10(X) X(0) X(1) X(2) X(3) X(4) X(5) X(6) X(7) X(8) X(9)

// 256 threads (4 waves, 1 wave/SIMD) + waves_per_eu(1,1) -> 512-reg unified
// budget per wave. Weight residency: 96 A-frags = 384 regs + 32 acc + working
// ~= 490 < 512. This is the whole point of this round: NO loop spill.
__attribute__((amdgpu_waves_per_eu(1, 1)))
__global__ void __launch_bounds__(256)
kan_seq(const float* __restrict__ x,
        const float* __restrict__ coef1,
        const float* __restrict__ sb1,
        const float* __restrict__ sp1,
        const float* __restrict__ coef2,
        const float* __restrict__ sb2,
        const float* __restrict__ sp2,
        float* __restrict__ out)
{
    // per-wave feature scratch: 40 records x 16B (wave-local, no barrier needed)
    __shared__ __align__(16) unsigned int scr[4][RPW][4];
    // per-wave silu K-tiles: 64 bf16 slots (40 used, 41..63 stay zero forever)
    __shared__ __align__(16) unsigned short scrS[4][64];
    // double-buffered MFMA wave-partials (4 waves)
    __shared__ __align__(16) float part[2][4][NHID];
    __shared__ float Hf[NHID][9];                        // epilogue h-features

    const int tid  = threadIdx.x;
    const int b    = blockIdx.x;      // one batch row per block
    const int lane = tid & 63;
    const int w    = tid >> 6;        // wave 0..3: owns records w*40 .. w*40+39
    const int arow = lane & 15;       // A-frag m index (o within tile)
    const int agrp = lane >> 4;       // k-group (0..3)
    const int recL = w * RPW + lane;  // record owned by this lane (if lane<40)

    // ---- one-time: A-fragments -> 96 NAMED uint4 regs ----
    // k=0..9:  spline weights sp1*coef1 (mapping verified PASS rounds 3-7)
    // k=10,11: silu weights sb1 as 2 K-tiles (k-slot = record idx, pad>=40 -> 0)
#define DECLW(k) uint4 wf##k##_0, wf##k##_1, wf##k##_2, wf##k##_3, \
                       wf##k##_4, wf##k##_5, wf##k##_6, wf##k##_7;
    K10(DECLW) DECLW(10) DECLW(11)
#undef DECLW

#define INITW1(k,t) { \
    int rec = w * RPW + (k) * 4 + agrp; \
    int oo  = (t) * 16 + arow; \
    const float4* cp = (const float4*)(coef1 + (size_t)(rec * NHID + oo) * 8); \
    float sp = sp1[rec * NHID + oo]; \
    float4 c0 = cp[0], c1 = cp[1]; \
    wf##k##_##t = make_uint4(packbf(sp * c0.x, sp * c0.y), packbf(sp * c0.z, sp * c0.w), \
                             packbf(sp * c1.x, sp * c1.y), packbf(sp * c1.z, sp * c1.w)); }
#define INITWK(k) INITW1(k,0) INITW1(k,1) INITW1(k,2) INITW1(k,3) \
                  INITW1(k,4) INITW1(k,5) INITW1(k,6) INITW1(k,7)
    K10(INITWK)
#undef INITWK
#undef INITW1

#define INITS1(k,t) { \
    int oo = (t) * 16 + arow; \
    int rbs = ((k) - 10) * 32 + agrp * 8; \
    int wbase = w * RPW; \
    float e0 = sb1_pad(sb1, wbase, rbs + 0, oo), e1 = sb1_pad(sb1, wbase, rbs + 1, oo); \
    float e2 = sb1_pad(sb1, wbase, rbs + 2, oo), e3 = sb1_pad(sb1, wbase, rbs + 3, oo); \
    float e4 = sb1_pad(sb1, wbase, rbs + 4, oo), e5 = sb1_pad(sb1, wbase, rbs + 5, oo); \
    float e6 = sb1_pad(sb1, wbase, rbs + 6, oo), e7 = sb1_pad(sb1, wbase, rbs + 7, oo); \
    wf##k##_##t = make_uint4(packbf(e0, e1), packbf(e2, e3), packbf(e4, e5), packbf(e6, e7)); }
#define INITSK(k) INITS1(k,0) INITS1(k,1) INITS1(k,2) INITS1(k,3) \
                  INITS1(k,4) INITS1(k,5) INITS1(k,6) INITS1(k,7)
    INITSK(10) INITSK(11)
#undef INITSK
#undef INITS1

    // h0 = 0: zero part (2*4*128 = 1024 floats) and silu tiles (128 uints)
    #pragma unroll
    for (int z = 0; z < 4; ++z) ((float*)part)[tid + 256 * z] = 0.f;
    if (tid < 128) ((unsigned int*)scrS)[tid] = 0u;
    float xv = 0.f;
    if (w == 0 && lane < NIN) xv = x[(size_t)b * SEQT * NIN + lane];
    const f32x4 zq = {0.f, 0.f, 0.f, 0.f};            // hoisted acc seed
    __syncthreads();

    for (int t = 0; t < SEQT; ++t) {
        const int rb = t & 1, wb = rb ^ 1;

        // ---- phase 1 (wave-local): lanes 0..39 compute own records' features ----
        float xv_use = xv;
        if (w == 0 && lane < NIN) {   // early global prefetch (full timestep of slack)
            int tn = (t + 1 < SEQT) ? (t + 1) : t;
            xv = x[((size_t)b * SEQT + tn) * NIN + lane];
        }
        if (lane < RPW) {
            float c;
            if (recL < NIN) c = xv_use;
            else {
                int hi = recL - NIN;
                c = (part[rb][0][hi] + part[rb][1][hi])
                  + (part[rb][2][hi] + part[rb][3][hi]);
            }
            E8 ft = feat8(c);
            uint4 pk;
            pk.x = packbf(ft.e0, ft.e1); pk.y = packbf(ft.e2, ft.e3);
            pk.z = packbf(ft.e4, ft.e5); pk.w = packbf(ft.e6, ft.e7);
            *(uint4*)&scr[w][lane][0] = pk;
            scrS[w][lane] = (unsigned short)f2bfbits(ft.sil);
        }

        // ---- wave-local visibility: drain LDS, then read own B-frags ----
        asm volatile("s_waitcnt lgkmcnt(0)" ::: "memory");
        __builtin_amdgcn_sched_barrier(0);
        uint4 bq0 = *(const uint4*)&scr[w][agrp][0];
        uint4 bq1 = *(const uint4*)&scr[w][4 + agrp][0];

        // ---- 96 MFMAs (10 spline + 2 silu K-tiles) x 8 o-tiles, all-resident A ----
        f32x4 ac0, ac1, ac2, ac3, ac4, ac5, ac6, ac7;
#define MMROW0(k, bqv) { s16x8 bb_ = __builtin_bit_cast(s16x8, bqv); \
        ac0 = __builtin_amdgcn_mfma_f32_16x16x32_bf16(__builtin_bit_cast(s16x8, wf##k##_0), bb_, zq, 0, 0, 0); \
        ac1 = __builtin_amdgcn_mfma_f32_16x16x32_bf16(__builtin_bit_cast(s16x8, wf##k##_1), bb_, zq, 0, 0, 0); \
        ac2 = __builtin_amdgcn_mfma_f32_16x16x32_bf16(__builtin_bit_cast(s16x8, wf##k##_2), bb_, zq, 0, 0, 0); \
        ac3 = __builtin_amdgcn_mfma_f32_16x16x32_bf16(__builtin_bit_cast(s16x8, wf##k##_3), bb_, zq, 0, 0, 0); \
        ac4 = __builtin_amdgcn_mfma_f32_16x16x32_bf16(__builtin_bit_cast(s16x8, wf##k##_4), bb_, zq, 0, 0, 0); \
        ac5 = __builtin_amdgcn_mfma_f32_16x16x32_bf16(__builtin_bit_cast(s16x8, wf##k##_5), bb_, zq, 0, 0, 0); \
        ac6 = __builtin_amdgcn_mfma_f32_16x16x32_bf16(__builtin_bit_cast(s16x8, wf##k##_6), bb_, zq, 0, 0, 0); \
        ac7 = __builtin_amdgcn_mfma_f32_16x16x32_bf16(__builtin_bit_cast(s16x8, wf##k##_7), bb_, zq, 0, 0, 0); }
#define MMROW(k, bqv) { s16x8 bb_ = __builtin_bit_cast(s16x8, bqv); \
        ac0 = __builtin_amdgcn_mfma_f32_16x16x32_bf16(__builtin_bit_cast(s16x8, wf##k##_0), bb_, ac0, 0, 0, 0); \
        ac1 = __builtin_amdgcn_mfma_f32_16x16x32_bf16(__builtin_bit_cast(s16x8, wf##k##_1), bb_, ac1, 0, 0, 0); \
        ac2 = __builtin_amdgcn_mfma_f32_16x16x32_bf16(__builtin_bit_cast(s16x8, wf##k##_2), bb_, ac2, 0, 0, 0); \
        ac3 = __builtin_amdgcn_mfma_f32_16x16x32_bf16(__builtin_bit_cast(s16x8, wf##k##_3), bb_, ac3, 0, 0, 0); \
        ac4 = __builtin_amdgcn_mfma_f32_16x16x32_bf16(__builtin_bit_cast(s16x8, wf##k##_4), bb_, ac4, 0, 0, 0); \
        ac5 = __builtin_amdgcn_mfma_f32_16x16x32_bf16(__builtin_bit_cast(s16x8, wf##k##_5), bb_, ac5, 0, 0, 0); \
        ac6 = __builtin_amdgcn_mfma_f32_16x16x32_bf16(__builtin_bit_cast(s16x8, wf##k##_6), bb_, ac6, 0, 0, 0); \
        ac7 = __builtin_amdgcn_mfma_f32_16x16x32_bf16(__builtin_bit_cast(s16x8, wf##k##_7), bb_, ac7, 0, 0, 0); }
        MMROW0(0, bq0)  uint4 bq2 = *(const uint4*)&scr[w][8 + agrp][0];
        MMROW(1, bq1)   uint4 bq3 = *(const uint4*)&scr[w][12 + agrp][0];
        MMROW(2, bq2)   uint4 bq4 = *(const uint4*)&scr[w][16 + agrp][0];
        MMROW(3, bq3)   uint4 bq5 = *(const uint4*)&scr[w][20 + agrp][0];
        MMROW(4, bq4)   uint4 bq6 = *(const uint4*)&scr[w][24 + agrp][0];
        MMROW(5, bq5)   uint4 bq7 = *(const uint4*)&scr[w][28 + agrp][0];
        MMROW(6, bq6)   uint4 bq8 = *(const uint4*)&scr[w][32 + agrp][0];
        MMROW(7, bq7)   uint4 bq9 = *(const uint4*)&scr[w][36 + agrp][0];
        MMROW(8, bq8)   uint4 bs0 = *(const uint4*)&scrS[w][agrp * 8];
        MMROW(9, bq9)   uint4 bs1 = *(const uint4*)&scrS[w][32 + agrp * 8];
        MMROW(10, bs0)
        MMROW(11, bs1)
#undef MMROW
#undef MMROW0

        // ---- write MFMA partials: lane holds D[m=agrp*4+j][n=arow]; lanes with
        //      arow==tt store o-tile tt (verified mapping, rounds 3-7 PASS) ----
#define WRR(tt) if (arow == (tt)) \
            *(f32x4*)&part[wb][w][(tt) * 16 + (agrp << 2)] = ac##tt;
        O8(WRR)
#undef WRR
        __syncthreads();   // the ONE barrier: part[wb] ready for t+1
    }

    // ---- layer 2 on final h only (SEQT even -> final partials in part[0]) ----
    if (tid < NHID) {
        float c = (part[0][0][tid] + part[0][1][tid])
                + (part[0][2][tid] + part[0][3][tid]);
        E8 ft = feat8(c);
        Hf[tid][0] = ft.e0; Hf[tid][1] = ft.e1; Hf[tid][2] = ft.e2; Hf[tid][3] = ft.e3;
        Hf[tid][4] = ft.e4; Hf[tid][5] = ft.e5; Hf[tid][6] = ft.e6; Hf[tid][7] = ft.e7;
        Hf[tid][8] = ft.sil;
    }
    __syncthreads();
    if (tid < 128) {
        int o2 = tid & 15, isg = tid >> 4;     // 8 i-groups of 16
        float acc = 0.f;
        for (int q = 0; q < 16; ++q) {
            int i = isg * 16 + q;
            const float* c2 = coef2 + (size_t)(i * NOUT + o2) * 8;
            float s = 0.f;
            #pragma unroll
            for (int k = 0; k < 8; ++k) s += Hf[i][k] * c2[k];
            acc += Hf[i][8] * sb2[i * NOUT + o2] + sp2[i * NOUT + o2] * s;
        }
        ((float*)part)[isg * 16 + o2] = acc;
    }
    __syncthreads();
    if (tid < NOUT) {
        float a = 0.f;
        #pragma unroll
        for (int g = 0; g < 8; ++g) a += ((float*)part)[g * 16 + tid];
        out[(size_t)b * NOUT + tid] = a;
    }
}

extern "C" void kernel_launch(void* const* d_in, const int* in_sizes, int n_in,
                              void* d_out, int out_size, void* d_ws, size_t ws_size,
                              hipStream_t stream) {
    kan_seq<<<NB, 256, 0, stream>>>(
        (const float*)d_in[0], (const float*)d_in[1], (const float*)d_in[2],
        (const float*)d_in[3], (const float*)d_in[4], (const float*)d_in[5],
        (const float*)d_in[6], (float*)d_out);
}

// Round 10
// 1219.119 us; speedup vs baseline: 1.2792x; 1.2792x over previous
//
#include <hip/hip_runtime.h>
#include <hip/hip_bf16.h>

#define NIN 32
#define NHID 128
#define NOUT 16
#define SEQT 512
#define NB 256
#define RPW 40     // records per K-quarter (4 quarters x 40 = 160)

typedef __attribute__((ext_vector_type(8))) short s16x8;   // 8 bf16 (4 VGPRs) - MFMA A/B frag
typedef __attribute__((ext_vector_type(4))) float f32x4;   // MFMA C/D frag

// manual RNE f32->bf16 (inputs are finite/sane here)
__device__ __forceinline__ unsigned int f2bfbits(float f) {
    unsigned int u = __float_as_uint(f);
    return (u + 0x7fffu + ((u >> 16) & 1u)) >> 16;
}
__device__ __forceinline__ unsigned int packbf(float lo, float hi) {
    return f2bfbits(lo) | (f2bfbits(hi) << 16);
}

__device__ __forceinline__ float fsilu(float c) {
    return c * __builtin_amdgcn_rcpf(1.f + __expf(-c));
}

// Knots: t_m = -8.8 + 1.6*m (G=5, K=3, range [-4,4]); uniform -> closed-form
// cubic basis. No local arrays; cndmask trees on NAMED scalars.
// Verified PASS rounds 6-8 (absmax identical to original recursion).
struct E8 { float e0, e1, e2, e3, e4, e5, e6, e7, sil; };

__device__ __forceinline__ E8 feat8(float c) {
    const float t0 = -8.8f, inv_h = 0.625f;
    float u  = (c - t0) * inv_h;
    float uf = floorf(u);
    int   m0 = (int)uf;
    bool valid = (m0 >= 0) && (m0 <= 10);
    float f   = u - uf;
    float omf = 1.0f - f;
    float f2 = f * f, f3 = f2 * f;
    float omf3 = omf * omf * omf;
    const float c6 = 0.16666667f;
    float v0 = omf3 * c6;
    float v1 = __builtin_fmaf(3.0f, f3, __builtin_fmaf(-6.0f, f2, 4.0f)) * c6;
    float v2 = __builtin_fmaf(-3.0f, f3, __builtin_fmaf(3.0f, f + f2, 1.0f)) * c6;
    float v3 = f3 * c6;
    int jb = m0 - 3;
    int js = jb < 0 ? 0 : (jb > 4 ? 4 : jb);
    E8 r;
    r.sil = fsilu(c);
#define SELK(k) { int d = (k) - js; int idx = (k) - jb; \
    float s = (idx == 0) ? v0 : (idx == 1) ? v1 : (idx == 2) ? v2 : (idx == 3) ? v3 : 0.f; \
    r.e##k = (valid && d >= 0 && d <= 3) ? s : 0.f; }
    SELK(0) SELK(1) SELK(2) SELK(3) SELK(4) SELK(5) SELK(6) SELK(7)
#undef SELK
    return r;
}

// sb1 with K-pad guard (r >= RPW -> 0, address stays in-bounds)
__device__ __forceinline__ float sb1_pad(const float* __restrict__ sb1, int wbase, int r, int oo) {
    int rr = (r < RPW) ? r : 0;
    float v = sb1[(wbase + rr) * NHID + oo];
    return (r < RPW) ? v : 0.f;
}

// ---- X-macro lists ----
#define O4(X) X(0) X(1) X(2) X(3)
#define K10(X) X(0) X(1) X(2) X(3) X(4) X(5) X(6) X(7) X(8) X(9)

// 512 threads, 8 waves, 2 waves/EU -> 256-reg budget per wave.
// Wave (kq=w>>1, oh=w&1): 40 records x 64 outputs.
// Resident: 48 weight quads (192) + 4 acc quads (16) + zq (4) + staging/addr
// ~= 235 < 256. THE point of this round: demand finally fits the budget.
__attribute__((amdgpu_waves_per_eu(2, 2)))
__global__ void __launch_bounds__(512)
kan_seq(const float* __restrict__ x,
        const float* __restrict__ coef1,
        const float* __restrict__ sb1,
        const float* __restrict__ sp1,
        const float* __restrict__ coef2,
        const float* __restrict__ sb2,
        const float* __restrict__ sp2,
        float* __restrict__ out)
{
    // per-wave feature scratch: 40 records x 16B (wave-local, no barrier needed;
    // waves of a K-quarter pair compute the same features redundantly)
    __shared__ __align__(16) unsigned int scr[8][RPW][4];
    // per-wave silu K-tiles: 64 bf16 slots (40 used, 40..63 stay zero forever)
    __shared__ __align__(16) unsigned short scrS[8][64];
    // double-buffered partials: [buf][kq][o] (both oh-waves write disjoint halves)
    __shared__ __align__(16) float part[2][4][NHID];
    __shared__ float Hf[NHID][9];                        // epilogue h-features

    const int tid  = threadIdx.x;
    const int b    = blockIdx.x;      // one batch row per block
    const int lane = tid & 63;
    const int w    = tid >> 6;        // wave 0..7
    const int kq   = w >> 1;          // K-quarter 0..3: records kq*40..+39
    const int oh   = w & 1;           // output half: o in [oh*64, oh*64+64)
    const int arow = lane & 15;       // A-frag m index (o within 16-tile)
    const int agrp = lane >> 4;       // k-group (0..3)
    const int recL = kq * RPW + lane; // record owned by this lane (if lane<40)

    // ---- one-time: A-fragments -> 48 NAMED uint4 regs ----
    // k=0..9:  spline weights sp1*coef1 (mapping verified PASS rounds 3-8)
    // k=10,11: silu weights sb1 as 2 K-tiles (k-slot = record idx, pad>=40 -> 0)
#define DECLW(k) uint4 wf##k##_0, wf##k##_1, wf##k##_2, wf##k##_3;
    K10(DECLW) DECLW(10) DECLW(11)
#undef DECLW

#define INITW1(k,t) { \
    int rec = kq * RPW + (k) * 4 + agrp; \
    int oo  = oh * 64 + (t) * 16 + arow; \
    const float4* cp = (const float4*)(coef1 + (size_t)(rec * NHID + oo) * 8); \
    float sp = sp1[rec * NHID + oo]; \
    float4 c0 = cp[0], c1 = cp[1]; \
    wf##k##_##t = make_uint4(packbf(sp * c0.x, sp * c0.y), packbf(sp * c0.z, sp * c0.w), \
                             packbf(sp * c1.x, sp * c1.y), packbf(sp * c1.z, sp * c1.w)); }
#define INITWK(k) INITW1(k,0) INITW1(k,1) INITW1(k,2) INITW1(k,3)
    K10(INITWK)
#undef INITWK
#undef INITW1

#define INITS1(k,t) { \
    int oo = oh * 64 + (t) * 16 + arow; \
    int rbs = ((k) - 10) * 32 + agrp * 8; \
    int wbase = kq * RPW; \
    float e0 = sb1_pad(sb1, wbase, rbs + 0, oo), e1 = sb1_pad(sb1, wbase, rbs + 1, oo); \
    float e2 = sb1_pad(sb1, wbase, rbs + 2, oo), e3 = sb1_pad(sb1, wbase, rbs + 3, oo); \
    float e4 = sb1_pad(sb1, wbase, rbs + 4, oo), e5 = sb1_pad(sb1, wbase, rbs + 5, oo); \
    float e6 = sb1_pad(sb1, wbase, rbs + 6, oo), e7 = sb1_pad(sb1, wbase, rbs + 7, oo); \
    wf##k##_##t = make_uint4(packbf(e0, e1), packbf(e2, e3), packbf(e4, e5), packbf(e6, e7)); }
#define INITSK(k) INITS1(k,0) INITS1(k,1) INITS1(k,2) INITS1(k,3)
    INITSK(10) INITSK(11)
#undef INITSK
#undef INITS1

    // h0 = 0: zero part (2*4*128 = 1024 floats) and silu tiles (256 uints)
    ((float*)part)[tid] = 0.f;
    ((float*)part)[tid + 512] = 0.f;
    if (tid < 256) ((unsigned int*)scrS)[tid] = 0u;
    float xv = 0.f;
    if (w < 2 && lane < NIN) xv = x[(size_t)b * SEQT * NIN + lane];
    const f32x4 zq = {0.f, 0.f, 0.f, 0.f};            // hoisted acc seed
    __syncthreads();

    for (int t = 0; t < SEQT; ++t) {
        const int rb = t & 1, wb = rb ^ 1;

        // ---- phase 1 (wave-local): lanes 0..39 compute own records' features ----
        float xv_use = xv;
        if (w < 2 && lane < NIN) {   // early global prefetch (full timestep of slack)
            int tn = (t + 1 < SEQT) ? (t + 1) : t;
            xv = x[((size_t)b * SEQT + tn) * NIN + lane];
        }
        if (lane < RPW) {
            float c;
            if (recL < NIN) c = xv_use;
            else {
                int hi = recL - NIN;
                c = (part[rb][0][hi] + part[rb][1][hi])
                  + (part[rb][2][hi] + part[rb][3][hi]);
            }
            E8 ft = feat8(c);
            uint4 pk;
            pk.x = packbf(ft.e0, ft.e1); pk.y = packbf(ft.e2, ft.e3);
            pk.z = packbf(ft.e4, ft.e5); pk.w = packbf(ft.e6, ft.e7);
            *(uint4*)&scr[w][lane][0] = pk;
            scrS[w][lane] = (unsigned short)f2bfbits(ft.sil);
        }

        // ---- wave-local visibility: drain LDS, then read own B-frags ----
        asm volatile("s_waitcnt lgkmcnt(0)" ::: "memory");
        __builtin_amdgcn_sched_barrier(0);
        uint4 bq0 = *(const uint4*)&scr[w][agrp][0];
        uint4 bq1 = *(const uint4*)&scr[w][4 + agrp][0];

        // ---- 48 MFMAs (10 spline + 2 silu K-tiles) x 4 o-tiles, resident A ----
        f32x4 ac0, ac1, ac2, ac3;
#define MMROW0(k, bqv) { s16x8 bb_ = __builtin_bit_cast(s16x8, bqv); \
        ac0 = __builtin_amdgcn_mfma_f32_16x16x32_bf16(__builtin_bit_cast(s16x8, wf##k##_0), bb_, zq, 0, 0, 0); \
        ac1 = __builtin_amdgcn_mfma_f32_16x16x32_bf16(__builtin_bit_cast(s16x8, wf##k##_1), bb_, zq, 0, 0, 0); \
        ac2 = __builtin_amdgcn_mfma_f32_16x16x32_bf16(__builtin_bit_cast(s16x8, wf##k##_2), bb_, zq, 0, 0, 0); \
        ac3 = __builtin_amdgcn_mfma_f32_16x16x32_bf16(__builtin_bit_cast(s16x8, wf##k##_3), bb_, zq, 0, 0, 0); }
#define MMROW(k, bqv) { s16x8 bb_ = __builtin_bit_cast(s16x8, bqv); \
        ac0 = __builtin_amdgcn_mfma_f32_16x16x32_bf16(__builtin_bit_cast(s16x8, wf##k##_0), bb_, ac0, 0, 0, 0); \
        ac1 = __builtin_amdgcn_mfma_f32_16x16x32_bf16(__builtin_bit_cast(s16x8, wf##k##_1), bb_, ac1, 0, 0, 0); \
        ac2 = __builtin_amdgcn_mfma_f32_16x16x32_bf16(__builtin_bit_cast(s16x8, wf##k##_2), bb_, ac2, 0, 0, 0); \
        ac3 = __builtin_amdgcn_mfma_f32_16x16x32_bf16(__builtin_bit_cast(s16x8, wf##k##_3), bb_, ac3, 0, 0, 0); }
        MMROW0(0, bq0)  uint4 bq2 = *(const uint4*)&scr[w][8 + agrp][0];
        MMROW(1, bq1)   uint4 bq3 = *(const uint4*)&scr[w][12 + agrp][0];
        MMROW(2, bq2)   uint4 bq4 = *(const uint4*)&scr[w][16 + agrp][0];
        MMROW(3, bq3)   uint4 bq5 = *(const uint4*)&scr[w][20 + agrp][0];
        MMROW(4, bq4)   uint4 bq6 = *(const uint4*)&scr[w][24 + agrp][0];
        MMROW(5, bq5)   uint4 bq7 = *(const uint4*)&scr[w][28 + agrp][0];
        MMROW(6, bq6)   uint4 bq8 = *(const uint4*)&scr[w][32 + agrp][0];
        MMROW(7, bq7)   uint4 bq9 = *(const uint4*)&scr[w][36 + agrp][0];
        MMROW(8, bq8)   uint4 bs0 = *(const uint4*)&scrS[w][agrp * 8];
        MMROW(9, bq9)   uint4 bs1 = *(const uint4*)&scrS[w][32 + agrp * 8];
        MMROW(10, bs0)
        MMROW(11, bs1)
#undef MMROW
#undef MMROW0

        // ---- write partials: lane holds D[m=agrp*4+j][n=arow]; lanes with
        //      arow==tt store o-tile tt (mapping verified rounds 3-8 PASS) ----
#define WRR(tt) if (arow == (tt)) \
            *(f32x4*)&part[wb][kq][oh * 64 + (tt) * 16 + (agrp << 2)] = ac##tt;
        O4(WRR)
#undef WRR
        __syncthreads();   // the ONE barrier: part[wb] ready for t+1
    }

    // ---- layer 2 on final h only (SEQT even -> final partials in part[0]) ----
    if (tid < NHID) {
        float c = (part[0][0][tid] + part[0][1][tid])
                + (part[0][2][tid] + part[0][3][tid]);
        E8 ft = feat8(c);
        Hf[tid][0] = ft.e0; Hf[tid][1] = ft.e1; Hf[tid][2] = ft.e2; Hf[tid][3] = ft.e3;
        Hf[tid][4] = ft.e4; Hf[tid][5] = ft.e5; Hf[tid][6] = ft.e6; Hf[tid][7] = ft.e7;
        Hf[tid][8] = ft.sil;
    }
    __syncthreads();
    if (tid < 128) {
        int o2 = tid & 15, isg = tid >> 4;     // 8 i-groups of 16
        float acc = 0.f;
        for (int q = 0; q < 16; ++q) {
            int i = isg * 16 + q;
            const float* c2 = coef2 + (size_t)(i * NOUT + o2) * 8;
            float s = 0.f;
            #pragma unroll
            for (int k = 0; k < 8; ++k) s += Hf[i][k] * c2[k];
            acc += Hf[i][8] * sb2[i * NOUT + o2] + sp2[i * NOUT + o2] * s;
        }
        ((float*)part)[isg * 16 + o2] = acc;
    }
    __syncthreads();
    if (tid < NOUT) {
        float a = 0.f;
        #pragma unroll
        for (int g = 0; g < 8; ++g) a += ((float*)part)[g * 16 + tid];
        out[(size_t)b * NOUT + tid] = a;
    }
}

extern "C" void kernel_launch(void* const* d_in, const int* in_sizes, int n_in,
                              void* d_out, int out_size, void* d_ws, size_t ws_size,
                              hipStream_t stream) {
    kan_seq<<<NB, 512, 0, stream>>>(
        (const float*)d_in[0], (const float*)d_in[1], (const float*)d_in[2],
        (const float*)d_in[3], (const float*)d_in[4], (const float*)d_in[5],
        (const float*)d_in[6], (float*)d_out);
}

// Round 11
// 1217.951 us; speedup vs baseline: 1.2804x; 1.0010x over previous
//
#include <hip/hip_runtime.h>
#include <hip/hip_bf16.h>

#define NIN 32
#define NHID 128
#define NOUT 16
#define SEQT 512
#define NB 256
#define RPH 80     // records per K-half (2 halves x 80 = 160)

typedef __attribute__((ext_vector_type(8))) short s16x8;   // 8 bf16 (4 VGPRs) - MFMA A/B frag
typedef __attribute__((ext_vector_type(4))) float f32x4;   // MFMA C/D frag

// manual RNE f32->bf16 (inputs are finite/sane here)
__device__ __forceinline__ unsigned int f2bfbits(float f) {
    unsigned int u = __float_as_uint(f);
    return (u + 0x7fffu + ((u >> 16) & 1u)) >> 16;
}
__device__ __forceinline__ unsigned int packbf(float lo, float hi) {
    return f2bfbits(lo) | (f2bfbits(hi) << 16);
}

__device__ __forceinline__ float fsilu(float c) {
    return c * __builtin_amdgcn_rcpf(1.f + __expf(-c));
}

// Knots: t_m = -8.8 + 1.6*m (G=5, K=3, range [-4,4]); uniform -> closed-form
// cubic basis. No local arrays; cndmask trees on NAMED scalars.
// Verified PASS rounds 6-10 (absmax identical to original recursion).
struct E8 { float e0, e1, e2, e3, e4, e5, e6, e7, sil; };

__device__ __forceinline__ E8 feat8(float c) {
    const float t0 = -8.8f, inv_h = 0.625f;
    float u  = (c - t0) * inv_h;
    float uf = floorf(u);
    int   m0 = (int)uf;
    bool valid = (m0 >= 0) && (m0 <= 10);
    float f   = u - uf;
    float omf = 1.0f - f;
    float f2 = f * f, f3 = f2 * f;
    float omf3 = omf * omf * omf;
    const float c6 = 0.16666667f;
    float v0 = omf3 * c6;
    float v1 = __builtin_fmaf(3.0f, f3, __builtin_fmaf(-6.0f, f2, 4.0f)) * c6;
    float v2 = __builtin_fmaf(-3.0f, f3, __builtin_fmaf(3.0f, f + f2, 1.0f)) * c6;
    float v3 = f3 * c6;
    int jb = m0 - 3;
    int js = jb < 0 ? 0 : (jb > 4 ? 4 : jb);
    E8 r;
    r.sil = fsilu(c);
#define SELK(k) { int d = (k) - js; int idx = (k) - jb; \
    float s = (idx == 0) ? v0 : (idx == 1) ? v1 : (idx == 2) ? v2 : (idx == 3) ? v3 : 0.f; \
    r.e##k = (valid && d >= 0 && d <= 3) ? s : 0.f; }
    SELK(0) SELK(1) SELK(2) SELK(3) SELK(4) SELK(5) SELK(6) SELK(7)
#undef SELK
    return r;
}

// sb1 with pad guard (slot r >= RPH -> 0, address stays in-bounds)
__device__ __forceinline__ float sb1_pad(const float* __restrict__ sb1, int base, int r, int oo) {
    int rr = (r < RPH) ? r : 0;
    float v = sb1[(base + rr) * NHID + oo];
    return (r < RPH) ? v : 0.f;
}

// ---- X-macro list for 20 spline K-tiles ----
#define K20(X) X(0) X(1) X(2) X(3) X(4) X(5) X(6) X(7) X(8) X(9) \
               X(10) X(11) X(12) X(13) X(14) X(15) X(16) X(17) X(18) X(19)

// 512 threads, 8 waves, 2 waves/EU -> 256-reg unified budget per wave.
// Wave (kh=w>>2, oq=w&3): 80 records x 32 outputs.
// Resident: 46 weight quads (184) + 2 acc quads (8) + zq (4) + bq staging (~10)
// + transients (~35) ~= 243 < 256. Goal of this round: kill the loop spill
// (R10 tell-tale: WRITE_SIZE 113 MB of scratch traffic).
__attribute__((amdgpu_waves_per_eu(2, 2)))
__global__ void __launch_bounds__(512)
kan_seq(const float* __restrict__ x,
        const float* __restrict__ coef1,
        const float* __restrict__ sb1,
        const float* __restrict__ sp1,
        const float* __restrict__ coef2,
        const float* __restrict__ sb2,
        const float* __restrict__ sp2,
        float* __restrict__ out)
{
    // shared feature store per K-half: 80 records x 16B (computed ONCE block-wide)
    __shared__ __align__(16) unsigned int scr[2][RPH][4];
    // silu K-tiles per K-half: 96 bf16 slots (80 used; 80..95 stay zero forever)
    __shared__ __align__(16) unsigned short scrS[2][96];
    // double-buffered partials: [buf][kh][o]
    __shared__ __align__(16) float part[2][2][NHID];
    __shared__ float Hf[NHID][9];                        // epilogue h-features

    const int tid  = threadIdx.x;
    const int b    = blockIdx.x;      // one batch row per block
    const int lane = tid & 63;
    const int w    = tid >> 6;        // wave 0..7
    const int kh   = w >> 2;          // K-half 0..1: records kh*80 .. +79
    const int oq   = w & 3;           // output quarter: o in [oq*32, oq*32+32)
    const int arow = lane & 15;       // A-frag m index (o within 16-tile)
    const int agrp = lane >> 4;       // k-group (0..3)
    const int rec20 = oq * 20 + lane; // record-within-half owned by lane (lane<20)

    // ---- one-time: A-fragments -> 46 NAMED uint4 regs ----
    // k=0..19: spline weights sp1*coef1 (mapping verified PASS rounds 3-10)
    // k=20..22: silu weights sb1 as 3 K-tiles (slot = record-in-half, pad>=80 -> 0)
#define DECLW(k) uint4 wf##k##_0, wf##k##_1;
    K20(DECLW) DECLW(20) DECLW(21) DECLW(22)
#undef DECLW

#define INITW1(k,t) { \
    int rec = kh * RPH + (k) * 4 + agrp; \
    int oo  = oq * 32 + (t) * 16 + arow; \
    const float4* cp = (const float4*)(coef1 + (size_t)(rec * NHID + oo) * 8); \
    float sp = sp1[rec * NHID + oo]; \
    float4 c0 = cp[0], c1 = cp[1]; \
    wf##k##_##t = make_uint4(packbf(sp * c0.x, sp * c0.y), packbf(sp * c0.z, sp * c0.w), \
                             packbf(sp * c1.x, sp * c1.y), packbf(sp * c1.z, sp * c1.w)); }
#define INITWK(k) INITW1(k,0) INITW1(k,1)
    K20(INITWK)
#undef INITWK

#define INITS1(k,t) { \
    int oo = oq * 32 + (t) * 16 + arow; \
    int rbs = ((k) - 20) * 32 + agrp * 8; \
    int base = kh * RPH; \
    float e0 = sb1_pad(sb1, base, rbs + 0, oo), e1 = sb1_pad(sb1, base, rbs + 1, oo); \
    float e2 = sb1_pad(sb1, base, rbs + 2, oo), e3 = sb1_pad(sb1, base, rbs + 3, oo); \
    float e4 = sb1_pad(sb1, base, rbs + 4, oo), e5 = sb1_pad(sb1, base, rbs + 5, oo); \
    float e6 = sb1_pad(sb1, base, rbs + 6, oo), e7 = sb1_pad(sb1, base, rbs + 7, oo); \
    wf##k##_##t = make_uint4(packbf(e0, e1), packbf(e2, e3), packbf(e4, e5), packbf(e6, e7)); }
    INITS1(20,0) INITS1(20,1) INITS1(21,0) INITS1(21,1) INITS1(22,0) INITS1(22,1)
#undef INITS1
#undef INITW1

    // h0 = 0: zero part (2*2*128 = 512 floats) and silu tiles (96 uints)
    ((float*)part)[tid] = 0.f;
    if (tid < 96) ((unsigned int*)scrS)[tid] = 0u;
    const bool ldx = (kh == 0) && (lane < 20) && (rec20 < NIN);
    float xv = 0.f;
    if (ldx) xv = x[(size_t)b * SEQT * NIN + rec20];
    const f32x4 zq = {0.f, 0.f, 0.f, 0.f};            // hoisted acc seed
    __syncthreads();

    for (int t = 0; t < SEQT; ++t) {
        const int rb = t & 1, wb = rb ^ 1;

        // ---- phase 1: each wave computes 20 records' features (NO redundancy;
        //      feature of record kh*80+rec20 computed exactly once block-wide) ----
        float xv_use = xv;
        if (ldx) {   // early global prefetch (full timestep of slack)
            int tn = (t + 1 < SEQT) ? (t + 1) : t;
            xv = x[((size_t)b * SEQT + tn) * NIN + rec20];
        }
        if (lane < 20) {
            int grec = kh * RPH + rec20;
            float c;
            if (grec < NIN) c = xv_use;   // only reachable for kh==0
            else {
                int hi = grec - NIN;
                c = part[rb][0][hi] + part[rb][1][hi];
            }
            E8 ft = feat8(c);
            uint4 pk;
            pk.x = packbf(ft.e0, ft.e1); pk.y = packbf(ft.e2, ft.e3);
            pk.z = packbf(ft.e4, ft.e5); pk.w = packbf(ft.e6, ft.e7);
            *(uint4*)&scr[kh][rec20][0] = pk;
            scrS[kh][rec20] = (unsigned short)f2bfbits(ft.sil);
        }
        __syncthreads();   // BARRIER A: features visible block-wide

        // ---- phase 2: 46 MFMAs (20 spline + 3 silu K-tiles) x 2 o-tiles,
        //      A-frags register-resident, B-frags 2-deep staged from LDS ----
        f32x4 ac0, ac1;
#define MMROW0(k, bqv) { s16x8 bb_ = __builtin_bit_cast(s16x8, bqv); \
        ac0 = __builtin_amdgcn_mfma_f32_16x16x32_bf16(__builtin_bit_cast(s16x8, wf##k##_0), bb_, zq, 0, 0, 0); \
        ac1 = __builtin_amdgcn_mfma_f32_16x16x32_bf16(__builtin_bit_cast(s16x8, wf##k##_1), bb_, zq, 0, 0, 0); }
#define MMROW(k, bqv) { s16x8 bb_ = __builtin_bit_cast(s16x8, bqv); \
        ac0 = __builtin_amdgcn_mfma_f32_16x16x32_bf16(__builtin_bit_cast(s16x8, wf##k##_0), bb_, ac0, 0, 0, 0); \
        ac1 = __builtin_amdgcn_mfma_f32_16x16x32_bf16(__builtin_bit_cast(s16x8, wf##k##_1), bb_, ac1, 0, 0, 0); }
        uint4 bqa = *(const uint4*)&scr[kh][agrp][0];
        uint4 bqb = *(const uint4*)&scr[kh][4 + agrp][0];
        MMROW0(0, bqa)  bqa = *(const uint4*)&scr[kh][8 + agrp][0];
        MMROW(1, bqb)   bqb = *(const uint4*)&scr[kh][12 + agrp][0];
        MMROW(2, bqa)   bqa = *(const uint4*)&scr[kh][16 + agrp][0];
        MMROW(3, bqb)   bqb = *(const uint4*)&scr[kh][20 + agrp][0];
        MMROW(4, bqa)   bqa = *(const uint4*)&scr[kh][24 + agrp][0];
        MMROW(5, bqb)   bqb = *(const uint4*)&scr[kh][28 + agrp][0];
        MMROW(6, bqa)   bqa = *(const uint4*)&scr[kh][32 + agrp][0];
        MMROW(7, bqb)   bqb = *(const uint4*)&scr[kh][36 + agrp][0];
        MMROW(8, bqa)   bqa = *(const uint4*)&scr[kh][40 + agrp][0];
        MMROW(9, bqb)   bqb = *(const uint4*)&scr[kh][44 + agrp][0];
        MMROW(10, bqa)  bqa = *(const uint4*)&scr[kh][48 + agrp][0];
        MMROW(11, bqb)  bqb = *(const uint4*)&scr[kh][52 + agrp][0];
        MMROW(12, bqa)  bqa = *(const uint4*)&scr[kh][56 + agrp][0];
        MMROW(13, bqb)  bqb = *(const uint4*)&scr[kh][60 + agrp][0];
        MMROW(14, bqa)  bqa = *(const uint4*)&scr[kh][64 + agrp][0];
        MMROW(15, bqb)  bqb = *(const uint4*)&scr[kh][68 + agrp][0];
        MMROW(16, bqa)  bqa = *(const uint4*)&scr[kh][72 + agrp][0];
        MMROW(17, bqb)  bqb = *(const uint4*)&scr[kh][76 + agrp][0];
        MMROW(18, bqa)  bqa = *(const uint4*)&scrS[kh][agrp * 8];
        MMROW(19, bqb)  bqb = *(const uint4*)&scrS[kh][32 + agrp * 8];
        MMROW(20, bqa)  bqa = *(const uint4*)&scrS[kh][64 + agrp * 8];
        MMROW(21, bqb)
        MMROW(22, bqa)
#undef MMROW
#undef MMROW0

        // ---- write partials: lanes with arow==tt store o-tile tt
        //      (fragment mapping verified rounds 3-10 PASS) ----
        if (arow == 0)
            *(f32x4*)&part[wb][kh][oq * 32 + (agrp << 2)] = ac0;
        if (arow == 1)
            *(f32x4*)&part[wb][kh][oq * 32 + 16 + (agrp << 2)] = ac1;
        __syncthreads();   // BARRIER B: part[wb] ready for t+1
    }

    // ---- layer 2 on final h only (SEQT even -> final partials in part[0]) ----
    if (tid < NHID) {
        float c = part[0][0][tid] + part[0][1][tid];
        E8 ft = feat8(c);
        Hf[tid][0] = ft.e0; Hf[tid][1] = ft.e1; Hf[tid][2] = ft.e2; Hf[tid][3] = ft.e3;
        Hf[tid][4] = ft.e4; Hf[tid][5] = ft.e5; Hf[tid][6] = ft.e6; Hf[tid][7] = ft.e7;
        Hf[tid][8] = ft.sil;
    }
    __syncthreads();
    if (tid < 128) {
        int o2 = tid & 15, isg = tid >> 4;     // 8 i-groups of 16
        float acc = 0.f;
        for (int q = 0; q < 16; ++q) {
            int i = isg * 16 + q;
            const float* c2 = coef2 + (size_t)(i * NOUT + o2) * 8;
            float s = 0.f;
            #pragma unroll
            for (int k = 0; k < 8; ++k) s += Hf[i][k] * c2[k];
            acc += Hf[i][8] * sb2[i * NOUT + o2] + sp2[i * NOUT + o2] * s;
        }
        ((float*)scr)[isg * 16 + o2] = acc;    // reuse scr as reduce buffer
    }
    __syncthreads();
    if (tid < NOUT) {
        float a = 0.f;
        #pragma unroll
        for (int g = 0; g < 8; ++g) a += ((float*)scr)[g * 16 + tid];
        out[(size_t)b * NOUT + tid] = a;
    }
}

extern "C" void kernel_launch(void* const* d_in, const int* in_sizes, int n_in,
                              void* d_out, int out_size, void* d_ws, size_t ws_size,
                              hipStream_t stream) {
    kan_seq<<<NB, 512, 0, stream>>>(
        (const float*)d_in[0], (const float*)d_in[1], (const float*)d_in[2],
        (const float*)d_in[3], (const float*)d_in[4], (const float*)d_in[5],
        (const float*)d_in[6], (float*)d_out);
}

// Round 12
// 1158.145 us; speedup vs baseline: 1.3465x; 1.0516x over previous
//
#include <hip/hip_runtime.h>
#include <hip/hip_bf16.h>

#define NIN 32
#define NHID 128
#define NOUT 16
#define SEQT 512
#define NB 256
#define RPH 80     // records per K-half (2 halves x 80 = 160)

typedef __attribute__((ext_vector_type(8))) short s16x8;   // 8 bf16 (4 VGPRs) - MFMA A/B frag
typedef __attribute__((ext_vector_type(4))) float f32x4;   // MFMA C/D frag

// manual RNE f32->bf16 (inputs are finite/sane here)
__device__ __forceinline__ unsigned int f2bfbits(float f) {
    unsigned int u = __float_as_uint(f);
    return (u + 0x7fffu + ((u >> 16) & 1u)) >> 16;
}
__device__ __forceinline__ unsigned int packbf(float lo, float hi) {
    return f2bfbits(lo) | (f2bfbits(hi) << 16);
}

__device__ __forceinline__ float fsilu(float c) {
    return c * __builtin_amdgcn_rcpf(1.f + __expf(-c));
}

// Knots: t_m = -8.8 + 1.6*m (G=5, K=3, range [-4,4]); uniform -> closed-form
// cubic basis. No local arrays; cndmask trees on NAMED scalars.
// Verified PASS rounds 6-11 (absmax identical to original recursion).
struct E8 { float e0, e1, e2, e3, e4, e5, e6, e7, sil; };

__device__ __forceinline__ E8 feat8(float c) {
    const float t0 = -8.8f, inv_h = 0.625f;
    float u  = (c - t0) * inv_h;
    float uf = floorf(u);
    int   m0 = (int)uf;
    bool valid = (m0 >= 0) && (m0 <= 10);
    float f   = u - uf;
    float omf = 1.0f - f;
    float f2 = f * f, f3 = f2 * f;
    float omf3 = omf * omf * omf;
    const float c6 = 0.16666667f;
    float v0 = omf3 * c6;
    float v1 = __builtin_fmaf(3.0f, f3, __builtin_fmaf(-6.0f, f2, 4.0f)) * c6;
    float v2 = __builtin_fmaf(-3.0f, f3, __builtin_fmaf(3.0f, f + f2, 1.0f)) * c6;
    float v3 = f3 * c6;
    int jb = m0 - 3;
    int js = jb < 0 ? 0 : (jb > 4 ? 4 : jb);
    E8 r;
    r.sil = fsilu(c);
#define SELK(k) { int d = (k) - js; int idx = (k) - jb; \
    float s = (idx == 0) ? v0 : (idx == 1) ? v1 : (idx == 2) ? v2 : (idx == 3) ? v3 : 0.f; \
    r.e##k = (valid && d >= 0 && d <= 3) ? s : 0.f; }
    SELK(0) SELK(1) SELK(2) SELK(3) SELK(4) SELK(5) SELK(6) SELK(7)
#undef SELK
    return r;
}

// sb1 with pad guard (slot r >= RPH -> 0, address stays in-bounds)
__device__ __forceinline__ float sb1_pad(const float* __restrict__ sb1, int base, int r, int oo) {
    int rr = (r < RPH) ? r : 0;
    float v = sb1[(base + rr) * NHID + oo];
    return (r < RPH) ? v : 0.f;
}

// ---- X-macro list for 20 spline K-tiles ----
#define K20(X) X(0) X(1) X(2) X(3) X(4) X(5) X(6) X(7) X(8) X(9) \
               X(10) X(11) X(12) X(13) X(14) X(15) X(16) X(17) X(18) X(19)

// ---- inline-asm MFMA, ALL operands in arch VGPRs (gfx950 allows v[] for
// A, B, C and D — cdna4_isa.md §10). This FORCES the weight quads out of the
// accum file: no v_accvgpr_read per MFMA, no 128-arch/128-accum split.
// (R9's failure was the "a" constraint; "v" compiles.)
#define MFZ(acv, av, bv, zv) asm("v_mfma_f32_16x16x32_bf16 %0, %1, %2, %3" \
    : "=&v"(acv) : "v"(av), "v"(bv), "v"(zv))
#define MFV(acv, av, bv) asm("v_mfma_f32_16x16x32_bf16 %0, %1, %2, %0" \
    : "+v"(acv) : "v"(av), "v"(bv))

// 512 threads, 8 waves, 2 waves/EU -> 256-reg budget per wave, now ALL arch:
// 46 weight quads (184) + 2 acc (8) + zq (4) + staging/transients (~50) ~= 246.
__attribute__((amdgpu_waves_per_eu(2, 2)))
__global__ void __launch_bounds__(512)
kan_seq(const float* __restrict__ x,
        const float* __restrict__ coef1,
        const float* __restrict__ sb1,
        const float* __restrict__ sp1,
        const float* __restrict__ coef2,
        const float* __restrict__ sb2,
        const float* __restrict__ sp2,
        float* __restrict__ out)
{
    // shared feature store per K-half: 80 records x 16B (computed ONCE block-wide)
    __shared__ __align__(16) unsigned int scr[2][RPH][4];
    // silu K-tiles per K-half: 96 bf16 slots (80 used; 80..95 stay zero forever)
    __shared__ __align__(16) unsigned short scrS[2][96];
    // double-buffered partials: [buf][kh][o]
    __shared__ __align__(16) float part[2][2][NHID];
    __shared__ float Hf[NHID][9];                        // epilogue h-features

    const int tid  = threadIdx.x;
    const int b    = blockIdx.x;      // one batch row per block
    const int lane = tid & 63;
    const int w    = tid >> 6;        // wave 0..7
    const int kh   = w >> 2;          // K-half 0..1: records kh*80 .. +79
    const int oq   = w & 3;           // output quarter: o in [oq*32, oq*32+32)
    const int arow = lane & 15;       // A-frag m index (o within 16-tile)
    const int agrp = lane >> 4;       // k-group (0..3)
    const int rec20 = oq * 20 + lane; // record-within-half owned by lane (lane<20)

    // ---- one-time: A-fragments -> 46 NAMED uint4 regs (arch-VGPR pinned via
    //      asm "v" uses). k=0..19: spline sp1*coef1; k=20..22: silu sb1.
    //      Mapping verified PASS rounds 3-11.
#define DECLW(k) uint4 wf##k##_0, wf##k##_1;
    K20(DECLW) DECLW(20) DECLW(21) DECLW(22)
#undef DECLW

#define INITW1(k,t) { \
    int rec = kh * RPH + (k) * 4 + agrp; \
    int oo  = oq * 32 + (t) * 16 + arow; \
    const float4* cp = (const float4*)(coef1 + (size_t)(rec * NHID + oo) * 8); \
    float sp = sp1[rec * NHID + oo]; \
    float4 c0 = cp[0], c1 = cp[1]; \
    wf##k##_##t = make_uint4(packbf(sp * c0.x, sp * c0.y), packbf(sp * c0.z, sp * c0.w), \
                             packbf(sp * c1.x, sp * c1.y), packbf(sp * c1.z, sp * c1.w)); }
#define INITWK(k) INITW1(k,0) INITW1(k,1)
    K20(INITWK)
#undef INITWK

#define INITS1(k,t) { \
    int oo = oq * 32 + (t) * 16 + arow; \
    int rbs = ((k) - 20) * 32 + agrp * 8; \
    int base = kh * RPH; \
    float e0 = sb1_pad(sb1, base, rbs + 0, oo), e1 = sb1_pad(sb1, base, rbs + 1, oo); \
    float e2 = sb1_pad(sb1, base, rbs + 2, oo), e3 = sb1_pad(sb1, base, rbs + 3, oo); \
    float e4 = sb1_pad(sb1, base, rbs + 4, oo), e5 = sb1_pad(sb1, base, rbs + 5, oo); \
    float e6 = sb1_pad(sb1, base, rbs + 6, oo), e7 = sb1_pad(sb1, base, rbs + 7, oo); \
    wf##k##_##t = make_uint4(packbf(e0, e1), packbf(e2, e3), packbf(e4, e5), packbf(e6, e7)); }
    INITS1(20,0) INITS1(20,1) INITS1(21,0) INITS1(21,1) INITS1(22,0) INITS1(22,1)
#undef INITS1
#undef INITW1

    // h0 = 0: zero part (2*2*128 = 512 floats) and silu tiles (96 uints)
    ((float*)part)[tid] = 0.f;
    if (tid < 96) ((unsigned int*)scrS)[tid] = 0u;
    const bool ldx = (kh == 0) && (lane < 20) && (rec20 < NIN);
    float xv = 0.f;
    if (ldx) xv = x[(size_t)b * SEQT * NIN + rec20];
    f32x4 zq = {0.f, 0.f, 0.f, 0.f};   // acc seed (arch VGPR via asm "v" use)
    __syncthreads();

    for (int t = 0; t < SEQT; ++t) {
        const int rb = t & 1, wb = rb ^ 1;

        // ---- phase 1: each wave computes 20 records' features (once block-wide) ----
        float xv_use = xv;
        if (ldx) {   // early global prefetch (full timestep of slack)
            int tn = (t + 1 < SEQT) ? (t + 1) : t;
            xv = x[((size_t)b * SEQT + tn) * NIN + rec20];
        }
        if (lane < 20) {
            int grec = kh * RPH + rec20;
            float c;
            if (grec < NIN) c = xv_use;   // only reachable for kh==0
            else {
                int hi = grec - NIN;
                c = part[rb][0][hi] + part[rb][1][hi];
            }
            E8 ft = feat8(c);
            uint4 pk;
            pk.x = packbf(ft.e0, ft.e1); pk.y = packbf(ft.e2, ft.e3);
            pk.z = packbf(ft.e4, ft.e5); pk.w = packbf(ft.e6, ft.e7);
            *(uint4*)&scr[kh][rec20][0] = pk;
            scrS[kh][rec20] = (unsigned short)f2bfbits(ft.sil);
        }
        __syncthreads();   // BARRIER A: features visible block-wide

        // ---- phase 2: 46 MFMAs (20 spline + 3 silu K-tiles) x 2 o-tiles,
        //      A register-resident (arch), B 2-deep staged from LDS ----
        f32x4 ac0, ac1;
#define MMROW0(k, bqv) { s16x8 bb_ = __builtin_bit_cast(s16x8, bqv); \
        MFZ(ac0, __builtin_bit_cast(s16x8, wf##k##_0), bb_, zq); \
        MFZ(ac1, __builtin_bit_cast(s16x8, wf##k##_1), bb_, zq); }
#define MMROW(k, bqv) { s16x8 bb_ = __builtin_bit_cast(s16x8, bqv); \
        MFV(ac0, __builtin_bit_cast(s16x8, wf##k##_0), bb_); \
        MFV(ac1, __builtin_bit_cast(s16x8, wf##k##_1), bb_); }
        uint4 bqa = *(const uint4*)&scr[kh][agrp][0];
        uint4 bqb = *(const uint4*)&scr[kh][4 + agrp][0];
        MMROW0(0, bqa)  bqa = *(const uint4*)&scr[kh][8 + agrp][0];
        MMROW(1, bqb)   bqb = *(const uint4*)&scr[kh][12 + agrp][0];
        MMROW(2, bqa)   bqa = *(const uint4*)&scr[kh][16 + agrp][0];
        MMROW(3, bqb)   bqb = *(const uint4*)&scr[kh][20 + agrp][0];
        MMROW(4, bqa)   bqa = *(const uint4*)&scr[kh][24 + agrp][0];
        MMROW(5, bqb)   bqb = *(const uint4*)&scr[kh][28 + agrp][0];
        MMROW(6, bqa)   bqa = *(const uint4*)&scr[kh][32 + agrp][0];
        MMROW(7, bqb)   bqb = *(const uint4*)&scr[kh][36 + agrp][0];
        MMROW(8, bqa)   bqa = *(const uint4*)&scr[kh][40 + agrp][0];
        MMROW(9, bqb)   bqb = *(const uint4*)&scr[kh][44 + agrp][0];
        MMROW(10, bqa)  bqa = *(const uint4*)&scr[kh][48 + agrp][0];
        MMROW(11, bqb)  bqb = *(const uint4*)&scr[kh][52 + agrp][0];
        MMROW(12, bqa)  bqa = *(const uint4*)&scr[kh][56 + agrp][0];
        MMROW(13, bqb)  bqb = *(const uint4*)&scr[kh][60 + agrp][0];
        MMROW(14, bqa)  bqa = *(const uint4*)&scr[kh][64 + agrp][0];
        MMROW(15, bqb)  bqb = *(const uint4*)&scr[kh][68 + agrp][0];
        MMROW(16, bqa)  bqa = *(const uint4*)&scr[kh][72 + agrp][0];
        MMROW(17, bqb)  bqb = *(const uint4*)&scr[kh][76 + agrp][0];
        MMROW(18, bqa)  bqa = *(const uint4*)&scrS[kh][agrp * 8];
        MMROW(19, bqb)  bqb = *(const uint4*)&scrS[kh][32 + agrp * 8];
        MMROW(20, bqa)  bqa = *(const uint4*)&scrS[kh][64 + agrp * 8];
        MMROW(21, bqb)
        MMROW(22, bqa)
#undef MMROW
#undef MMROW0

        // ---- MFMA(asm) -> LDS-read-of-acc hazard gap (compiler can't see into
        //      the asm), then write partials (mapping verified rounds 3-11) ----
        asm volatile("s_nop 7\n\ts_nop 7\n\ts_nop 7" :::);
        if (arow == 0)
            *(f32x4*)&part[wb][kh][oq * 32 + (agrp << 2)] = ac0;
        if (arow == 1)
            *(f32x4*)&part[wb][kh][oq * 32 + 16 + (agrp << 2)] = ac1;
        __syncthreads();   // BARRIER B: part[wb] ready for t+1
    }

    // ---- layer 2 on final h only (SEQT even -> final partials in part[0]) ----
    if (tid < NHID) {
        float c = part[0][0][tid] + part[0][1][tid];
        E8 ft = feat8(c);
        Hf[tid][0] = ft.e0; Hf[tid][1] = ft.e1; Hf[tid][2] = ft.e2; Hf[tid][3] = ft.e3;
        Hf[tid][4] = ft.e4; Hf[tid][5] = ft.e5; Hf[tid][6] = ft.e6; Hf[tid][7] = ft.e7;
        Hf[tid][8] = ft.sil;
    }
    __syncthreads();
    if (tid < 128) {
        int o2 = tid & 15, isg = tid >> 4;     // 8 i-groups of 16
        float acc = 0.f;
        for (int q = 0; q < 16; ++q) {
            int i = isg * 16 + q;
            const float* c2 = coef2 + (size_t)(i * NOUT + o2) * 8;
            float s = 0.f;
            #pragma unroll
            for (int k = 0; k < 8; ++k) s += Hf[i][k] * c2[k];
            acc += Hf[i][8] * sb2[i * NOUT + o2] + sp2[i * NOUT + o2] * s;
        }
        ((float*)scr)[isg * 16 + o2] = acc;    // reuse scr as reduce buffer
    }
    __syncthreads();
    if (tid < NOUT) {
        float a = 0.f;
        #pragma unroll
        for (int g = 0; g < 8; ++g) a += ((float*)scr)[g * 16 + tid];
        out[(size_t)b * NOUT + tid] = a;
    }
}

extern "C" void kernel_launch(void* const* d_in, const int* in_sizes, int n_in,
                              void* d_out, int out_size, void* d_ws, size_t ws_size,
                              hipStream_t stream) {
    kan_seq<<<NB, 512, 0, stream>>>(
        (const float*)d_in[0], (const float*)d_in[1], (const float*)d_in[2],
        (const float*)d_in[3], (const float*)d_in[4], (const float*)d_in[5],
        (const float*)d_in[6], (float*)d_out);
}